// Round 5
// baseline (5178.875 us; speedup 1.0000x reference)
//
#include <hip/hip_runtime.h>
#include <hip/hip_bf16.h>
#include <stdint.h>

// ============================================================================
// Mamba MixerModel (B=8, L=1024, d_model=1024, 4 layers) — bf16 MFMA round.
//
// All four GEMMs (in_proj, x_proj, dt_proj, out_proj) use
// v_mfma_f32_16x16x32_bf16 with the m97 structure: 128-wide tiles, BK=32,
// 4 waves/block, global_load_lds width-16 staging, single-LDS-buffer
// 2-barrier K-loop. Activations are bf16; accumulation fp32; LN/conv/scan
// math fp32 with bf16 I/O. Weights converted fp32->bf16 once per launch.
//
// Scan: 1 state per lane (16 lanes per (b,d) channel -> 4096 waves, 4/SIMD)
// + 4-step software pipeline (statically-indexed register arrays) to hide
// ~250cy load latency; shfl_xor tree reduce over the 16-lane state group.
// ============================================================================

constexpr int B_  = 8;
constexpr int L_  = 1024;
constexpr int DM  = 1024;   // d_model
constexpr int DI  = 2048;   // d_inner
constexpr int DS  = 16;     // d_state
constexpr int DR  = 64;     // dt_rank
constexpr int NL  = 4;
constexpr int M_  = B_ * L_; // 8192
constexpr float EPS_ = 1e-5f;

typedef __attribute__((ext_vector_type(8))) short  bf16x8;  // 8 bf16 (4 VGPRs)
typedef __attribute__((ext_vector_type(4))) float  f32x4;

// bf16 (as raw short) -> fp32, exact
__device__ __forceinline__ float bf2f(short s) {
    unsigned int u = ((unsigned int)(unsigned short)s) << 16;
    float f;
    __builtin_memcpy(&f, &u, 4);
    return f;
}

// async global->LDS, 16 bytes per lane (global_load_lds_dwordx4).
// NOTE: direct pointer casts (addrspacecast) — integer roundtrip would
// truncate the generic-space aperture address, not yield the LDS offset.
__device__ __forceinline__ void async_lds16(const void* g, void* l) {
    __builtin_amdgcn_global_load_lds(
        (const __attribute__((address_space(1))) void*)g,
        (__attribute__((address_space(3))) void*)l,
        16, 0, 0);
}

// ---------------------------------------------------------------------------
// fp32 -> bf16 elementwise convert (weights), grid-stride, 4 elems/thread
// ---------------------------------------------------------------------------
__launch_bounds__(256)
__global__ void cvt_bf16_kernel(const float* __restrict__ src,
                                __hip_bfloat16* __restrict__ dst, int n)
{
    for (int i = (blockIdx.x * 256 + threadIdx.x) * 4; i < n;
         i += gridDim.x * 256 * 4) {
        const float4 v = *reinterpret_cast<const float4*>(src + i);
        alignas(8) __hip_bfloat16 t[4];
        t[0] = __float2bfloat16(v.x); t[1] = __float2bfloat16(v.y);
        t[2] = __float2bfloat16(v.z); t[3] = __float2bfloat16(v.w);
        *reinterpret_cast<short4*>(dst + i) = *reinterpret_cast<short4*>(t);
    }
}

// ---------------------------------------------------------------------------
// residual add + LayerNorm. One block per row. OUTBF: write bf16 else fp32.
// ---------------------------------------------------------------------------
template<bool ADD, bool OUTBF>
__launch_bounds__(256)
__global__ void add_ln_kernel(const float* __restrict__ Hin,
                              float* __restrict__ R,
                              void* __restrict__ Xout,
                              const float* __restrict__ w,
                              const float* __restrict__ bz)
{
    const int row = blockIdx.x;
    const int tid = threadIdx.x;
    const size_t off = (size_t)row * DM + (size_t)tid * 4;

    float4 v = *reinterpret_cast<const float4*>(Hin + off);
    if (ADD) {
        const float4 r = *reinterpret_cast<const float4*>(R + off);
        v.x += r.x; v.y += r.y; v.z += r.z; v.w += r.w;
    }
    *reinterpret_cast<float4*>(R + off) = v;

    float s  = v.x + v.y + v.z + v.w;
    float ss = v.x*v.x + v.y*v.y + v.z*v.z + v.w*v.w;
    #pragma unroll
    for (int o = 32; o > 0; o >>= 1) {
        s  += __shfl_down(s, o);
        ss += __shfl_down(ss, o);
    }
    __shared__ float red[8];
    const int lane = tid & 63, wv = tid >> 6;
    if (lane == 0) { red[wv] = s; red[4 + wv] = ss; }
    __syncthreads();
    s  = red[0] + red[1] + red[2] + red[3];
    ss = red[4] + red[5] + red[6] + red[7];

    const float mu   = s * (1.0f / DM);
    const float var  = ss * (1.0f / DM) - mu * mu;
    const float rstd = rsqrtf(var + EPS_);

    const float4 w4 = *reinterpret_cast<const float4*>(w  + (size_t)tid * 4);
    const float4 b4 = *reinterpret_cast<const float4*>(bz + (size_t)tid * 4);
    float o[4];
    o[0] = (v.x - mu) * rstd * w4.x + b4.x;
    o[1] = (v.y - mu) * rstd * w4.y + b4.y;
    o[2] = (v.z - mu) * rstd * w4.z + b4.z;
    o[3] = (v.w - mu) * rstd * w4.w + b4.w;
    if (OUTBF) {
        alignas(8) __hip_bfloat16 t[4];
        #pragma unroll
        for (int j = 0; j < 4; ++j) t[j] = __float2bfloat16(o[j]);
        *reinterpret_cast<short4*>((__hip_bfloat16*)Xout + off) =
            *reinterpret_cast<short4*>(t);
    } else {
        float4 f; f.x = o[0]; f.y = o[1]; f.z = o[2]; f.w = o[3];
        *reinterpret_cast<float4*>((float*)Xout + off) = f;
    }
}

// ---------------------------------------------------------------------------
// bf16 MFMA GEMM (NT): C[m,n] = sum_k A[m,k]*Bw[n,k], fp32 accumulate.
// BK=32. 4 waves per 256-thread block, wave tile WM x WN (MR x NR frags).
// B tile always stages 128 rows (row index clamped for N=96 case).
// EPI: 0 fp32 C | 1 softplus(x+bias)->bf16 Cb | 2 fp32 C + bf16 Cb | 3 bf16 Cb
// ---------------------------------------------------------------------------
template<int BM, int BN, int WM, int WN, int EPI>
__launch_bounds__(256)
__global__ void gemm_bf16(const __hip_bfloat16* __restrict__ A, int lda,
                          const __hip_bfloat16* __restrict__ Bw, int ldb,
                          int N, int K,
                          float* __restrict__ C,
                          __hip_bfloat16* __restrict__ Cb, int ldc,
                          const float* __restrict__ bias)
{
    constexpr int BK = 32;
    constexpr int MR = WM / 16, NR = WN / 16;
    constexpr int NWN = BN / WN;
    static_assert((BM / WM) * NWN == 4, "4 waves");
    constexpr int CHA = BM * 4;   // 16B chunks in A tile (BM*BK*2/16)
    constexpr int CHB = 512;      // 128 rows * 4 chunks

    __shared__ __align__(16) __hip_bfloat16 As[BM * BK];
    __shared__ __align__(16) __hip_bfloat16 Bs[128 * BK];

    const int tid  = threadIdx.x;
    const int lane = tid & 63;
    const int wid  = tid >> 6;
    const int wr   = (wid / NWN) * WM;
    const int wc   = (wid % NWN) * WN;
    const int m0   = blockIdx.x * BM;
    const int n0   = blockIdx.y * BN;

    f32x4 acc[MR][NR];
    #pragma unroll
    for (int i = 0; i < MR; ++i)
        #pragma unroll
        for (int j = 0; j < NR; ++j)
            #pragma unroll
            for (int r = 0; r < 4; ++r) acc[i][j][r] = 0.f;

    const int fr = lane & 15;          // fragment row/col within 16
    const int kh = (lane >> 4) * 8;    // fragment k offset

    for (int k0 = 0; k0 < K; k0 += BK) {
        __syncthreads();   // previous iter's LDS reads complete
        #pragma unroll
        for (int c = tid; c < CHA; c += 256) {
            const int row = c >> 2, ck = (c & 3) * 8;
            async_lds16(A + (size_t)(m0 + row) * lda + k0 + ck, &As[c * 8]);
        }
        #pragma unroll
        for (int c = tid; c < CHB; c += 256) {
            const int row = c >> 2, ck = (c & 3) * 8;
            int rs = n0 + row; rs = rs < N ? rs : N - 1;  // clamp (N=96 tile)
            async_lds16(Bw + (size_t)rs * ldb + k0 + ck, &Bs[c * 8]);
        }
        asm volatile("s_waitcnt vmcnt(0)" ::: "memory");
        __syncthreads();

        bf16x8 af[MR], bfr[NR];
        #pragma unroll
        for (int mi = 0; mi < MR; ++mi)
            af[mi] = *reinterpret_cast<const bf16x8*>(
                &As[(wr + mi * 16 + fr) * BK + kh]);
        #pragma unroll
        for (int ni = 0; ni < NR; ++ni)
            bfr[ni] = *reinterpret_cast<const bf16x8*>(
                &Bs[(wc + ni * 16 + fr) * BK + kh]);
        #pragma unroll
        for (int mi = 0; mi < MR; ++mi)
            #pragma unroll
            for (int ni = 0; ni < NR; ++ni)
                acc[mi][ni] = __builtin_amdgcn_mfma_f32_16x16x32_bf16(
                    af[mi], bfr[ni], acc[mi][ni], 0, 0, 0);
    }

    // epilogue: D[row,col], col = lane&15, row = (lane>>4)*4 + r
    const int r0 = (lane >> 4) * 4;
    #pragma unroll
    for (int mi = 0; mi < MR; ++mi) {
        #pragma unroll
        for (int ni = 0; ni < NR; ++ni) {
            const int row = m0 + wr + mi * 16 + r0;
            const int col = n0 + wc + ni * 16 + fr;
            const float bv = (EPI == 1) ? bias[col] : 0.f;
            #pragma unroll
            for (int r = 0; r < 4; ++r) {
                float v = acc[mi][ni][r];
                if (EPI == 1) {
                    v += bv;
                    v = (v > 20.f) ? v : log1pf(expf(v));  // softplus
                }
                if (EPI == 0 || EPI == 2)
                    C[(size_t)(row + r) * ldc + col] = v;
                if (EPI >= 1)
                    Cb[(size_t)(row + r) * ldc + col] = __float2bfloat16(v);
            }
        }
    }
}

// ---------------------------------------------------------------------------
// causal depthwise conv (width 4) + bias + SiLU, bf16 in/out.
// One block per (b,l) row; each thread does 8 contiguous channels.
// ---------------------------------------------------------------------------
__launch_bounds__(256)
__global__ void conv_silu_kernel(const __hip_bfloat16* __restrict__ Xin,
                                 const float* __restrict__ cw,   // (DI,4)
                                 const float* __restrict__ cb,   // (DI)
                                 __hip_bfloat16* __restrict__ Xout)
{
    const int row = blockIdx.x;          // 0..M_-1
    const int l   = row & (L_ - 1);
    const int c0  = threadIdx.x * 8;

    float xv[4][8];
    #pragma unroll
    for (int k = 0; k < 4; ++k) {
        const int li = l - 3 + k;
        if (li >= 0) {
            const bf16x8 v = *reinterpret_cast<const bf16x8*>(
                Xin + (size_t)(row - 3 + k) * DI + c0);
            #pragma unroll
            for (int j = 0; j < 8; ++j)
                xv[k][j] = bf2f(v[j]);
        } else {
            #pragma unroll
            for (int j = 0; j < 8; ++j) xv[k][j] = 0.f;
        }
    }

    alignas(16) __hip_bfloat16 o[8];
    #pragma unroll
    for (int j = 0; j < 8; ++j) {
        const float4 w = *reinterpret_cast<const float4*>(cw + (size_t)(c0 + j) * 4);
        float a = cb[c0 + j];
        a = fmaf(w.x, xv[0][j], a);
        a = fmaf(w.y, xv[1][j], a);
        a = fmaf(w.z, xv[2][j], a);
        a = fmaf(w.w, xv[3][j], a);
        o[j] = __float2bfloat16(a / (1.f + __expf(-a)));   // silu
    }
    *reinterpret_cast<bf16x8*>(Xout + (size_t)row * DI + c0) =
        *reinterpret_cast<bf16x8*>(o);
}

// ---------------------------------------------------------------------------
// selective scan, fused with y = (scan + x*D) * silu(z).  bf16 x/dt/z in,
// bf16 y out, fp32 B/C (XDBL).
// Layout: 16 lanes per (b,d) channel, ONE state per lane (q = tid&15).
//   -> 4096 waves total (4 waves/SIMD of TLP), one v_exp per lane-step.
// 4-step software pipeline: batch-issue loads for steps l0+4..l0+7, compute
// steps l0..l0+3 from registers. All arrays statically indexed (full unroll)
// so nothing spills to scratch.
// ---------------------------------------------------------------------------
__launch_bounds__(256)
__global__ void scan_kernel(const __hip_bfloat16* __restrict__ XC,
                            const __hip_bfloat16* __restrict__ DT,
                            const float* __restrict__ XDBL,   // (M_, 96)
                            const __hip_bfloat16* __restrict__ Z,
                            __hip_bfloat16* __restrict__ Y,
                            const float* __restrict__ A_log,  // (DI, DS)
                            const float* __restrict__ Dp)     // (DI)
{
    const int tid = threadIdx.x;
    const int q   = tid & 15;          // state index 0..15
    const int dl  = tid >> 4;          // 0..15
    const int d   = blockIdx.x * 16 + dl;
    const int b   = blockIdx.y;

    const float Ac = -expf(A_log[(size_t)d * DS + q]);
    const float Dv = Dp[d];
    const size_t mb = (size_t)b * L_;
    float h = 0.f;

    // current 4-step operand window
    float xs[4], dts[4], zs[4], Bc[4], Cc[4];
    #pragma unroll
    for (int j = 0; j < 4; ++j) {
        const size_t m = mb + (size_t)j;
        xs[j]  = bf2f(*reinterpret_cast<const short*>(XC + m * DI + d));
        dts[j] = bf2f(*reinterpret_cast<const short*>(DT + m * DI + d));
        zs[j]  = bf2f(*reinterpret_cast<const short*>(Z  + m * DI + d));
        Bc[j]  = XDBL[m * 96 + DR + q];
        Cc[j]  = XDBL[m * 96 + DR + DS + q];
    }

    for (int l0 = 0; l0 < L_; l0 += 4) {
        // issue loads for the NEXT 4 steps first (latency hides under compute)
        float xn[4], dtn[4], zn[4], Bn[4], Cn[4];
        #pragma unroll
        for (int j = 0; j < 4; ++j) {
            const int ln = l0 + 4 + j;
            if (ln < L_) {
                const size_t m = mb + (size_t)ln;
                xn[j]  = bf2f(*reinterpret_cast<const short*>(XC + m * DI + d));
                dtn[j] = bf2f(*reinterpret_cast<const short*>(DT + m * DI + d));
                zn[j]  = bf2f(*reinterpret_cast<const short*>(Z  + m * DI + d));
                Bn[j]  = XDBL[m * 96 + DR + q];
                Cn[j]  = XDBL[m * 96 + DR + DS + q];
            } else {
                xn[j] = 0.f; dtn[j] = 0.f; zn[j] = 0.f; Bn[j] = 0.f; Cn[j] = 0.f;
            }
        }

        // compute the current 4 steps (operands already in registers)
        #pragma unroll
        for (int j = 0; j < 4; ++j) {
            const float dtv = dts[j];
            const float dA  = __expf(dtv * Ac);
            h = fmaf(dA, h, (dtv * xs[j]) * Bc[j]);
            float y = h * Cc[j];
            y += __shfl_xor(y, 1);
            y += __shfl_xor(y, 2);
            y += __shfl_xor(y, 4);
            y += __shfl_xor(y, 8);
            if (q == 0) {
                const float yo = fmaf(xs[j], Dv, y);
                const float g  = zs[j] / (1.f + __expf(-zs[j]));   // silu(z)
                Y[(mb + (size_t)(l0 + j)) * DI + d] = __float2bfloat16(yo * g);
            }
        }

        #pragma unroll
        for (int j = 0; j < 4; ++j) {
            xs[j] = xn[j]; dts[j] = dtn[j]; zs[j] = zn[j];
            Bc[j] = Bn[j]; Cc[j]  = Cn[j];
        }
    }
}

// ---------------------------------------------------------------------------
extern "C" void kernel_launch(void* const* d_in, const int* in_sizes, int n_in,
                              void* d_out, int out_size, void* d_ws, size_t ws_size,
                              hipStream_t stream)
{
    (void)in_sizes; (void)n_in; (void)out_size; (void)ws_size;

    const float* hs   = (const float*)d_in[0];
    const float* inw  = (const float*)d_in[1];
    const float* cw   = (const float*)d_in[2];
    const float* cb   = (const float*)d_in[3];
    const float* xpw  = (const float*)d_in[4];
    const float* dtw  = (const float*)d_in[5];
    const float* dtb  = (const float*)d_in[6];
    const float* alog = (const float*)d_in[7];
    const float* dpar = (const float*)d_in[8];
    const float* outw = (const float*)d_in[9];
    const float* nw   = (const float*)d_in[10];
    const float* nb   = (const float*)d_in[11];
    const float* nfw  = (const float*)d_in[12];
    const float* nfb  = (const float*)d_in[13];
    float* out = (float*)d_out;

    char* w = (char*)d_ws;
    const size_t MB = 1u << 20;
    float*          R     = (float*)(w);                  // 32 MB
    char*           PA    = w + 32  * MB;                 // 32 MB pool A
    char*           PB    = w + 64  * MB;                 // 32 MB pool B
    __hip_bfloat16* ZBb   = (__hip_bfloat16*)(w + 96  * MB);
    __hip_bfloat16* XCb   = (__hip_bfloat16*)(w + 128 * MB);
    float*          XDBL  = (float*)(w + 160 * MB);       // M_*96 fp32 (3 MB)
    __hip_bfloat16* XDBLb = (__hip_bfloat16*)(w + 164 * MB);
    __hip_bfloat16* W1b   = (__hip_bfloat16*)(w + 168 * MB);  // 32 MB
    __hip_bfloat16* Woutb = (__hip_bfloat16*)(w + 200 * MB);  // 16 MB
    __hip_bfloat16* XPWb  = (__hip_bfloat16*)(w + 216 * MB);  // 1.5 MB
    __hip_bfloat16* DTWb  = (__hip_bfloat16*)(w + 218 * MB);  // 1 MB

    // pool A roles: xc_pre (bf16) -> dt (bf16) -> H (fp32)
    __hip_bfloat16* XCpreb = (__hip_bfloat16*)PA;
    __hip_bfloat16* DTb    = (__hip_bfloat16*)PA;
    float*          H      = (float*)PA;
    // pool B roles: x_ln (bf16) -> y_gated (bf16)
    __hip_bfloat16* XLNb   = (__hip_bfloat16*)PB;
    __hip_bfloat16* DTYb   = (__hip_bfloat16*)PB;

    // weight conversion (whole stack, every launch — ws is re-poisoned)
    cvt_bf16_kernel<<<2048, 256, 0, stream>>>(inw,  W1b,   NL * 2 * DI * DM);
    cvt_bf16_kernel<<<1024, 256, 0, stream>>>(outw, Woutb, NL * DM * DI);
    cvt_bf16_kernel<<<256,  256, 0, stream>>>(xpw,  XPWb,  NL * 96 * DI);
    cvt_bf16_kernel<<<256,  256, 0, stream>>>(dtw,  DTWb,  NL * DI * DR);

    for (int i = 0; i < NL; ++i) {
        // residual add + LN -> bf16
        if (i == 0)
            add_ln_kernel<false, true><<<M_, 256, 0, stream>>>(
                hs, R, XLNb, nw + (size_t)i * DM, nb + (size_t)i * DM);
        else
            add_ln_kernel<true, true><<<M_, 256, 0, stream>>>(
                H, R, XLNb, nw + (size_t)i * DM, nb + (size_t)i * DM);

        // in_proj (xc half, z half) -> bf16
        const __hip_bfloat16* w1 = W1b + (size_t)i * 2 * DI * DM;
        gemm_bf16<128,128,64,64,3><<<dim3(M_/128, DI/128), 256, 0, stream>>>(
            XLNb, DM, w1, DM, DI, DM, nullptr, XCpreb, DI, nullptr);
        gemm_bf16<128,128,64,64,3><<<dim3(M_/128, DI/128), 256, 0, stream>>>(
            XLNb, DM, w1 + (size_t)DI * DM, DM, DI, DM, nullptr, ZBb, DI, nullptr);

        // causal depthwise conv + silu (bf16 -> bf16)
        conv_silu_kernel<<<M_, 256, 0, stream>>>(
            XCpreb, cw + (size_t)i * DI * 4, cb + (size_t)i * DI, XCb);

        // x_proj -> x_dbl (fp32 for scan B/C, bf16 for dt_proj A)
        gemm_bf16<32,96,16,48,2><<<dim3(M_/32, 1), 256, 0, stream>>>(
            XCb, DI, XPWb + (size_t)i * 96 * DI, DI, 96, DI,
            XDBL, XDBLb, 96, nullptr);

        // dt_proj + bias + softplus -> bf16 dt (overwrites dead xc_pre)
        gemm_bf16<128,128,64,64,1><<<dim3(M_/128, DI/128), 256, 0, stream>>>(
            XDBLb, 96, DTWb + (size_t)i * DI * DR, DR, DI, DR,
            nullptr, DTb, DI, dtb + (size_t)i * DI);

        // selective scan + D skip + silu(z) gating -> bf16 y (pool B)
        scan_kernel<<<dim3(DI/16, B_), 256, 0, stream>>>(
            XCb, DTb, XDBL, ZBb, DTYb,
            alog + (size_t)i * DI * DS, dpar + (size_t)i * DI);

        // out_proj -> H fp32 (pool A, dt now dead)
        gemm_bf16<128,128,64,64,0><<<dim3(M_/128, DM/128), 256, 0, stream>>>(
            DTYb, DI, Woutb + (size_t)i * DM * DI, DI, DM, DI,
            H, nullptr, DM, nullptr);
    }

    // final residual add + LN -> fp32 output
    add_ln_kernel<true, false><<<M_, 256, 0, stream>>>(H, R, out, nfw, nfb);
}